// Round 9
// baseline (393.515 us; speedup 1.0000x reference)
//
#include <hip/hip_runtime.h>
#include <hip/hip_bf16.h>

// Attention block: x[16,1024,768] -> QKV -> MHA(12 heads, d=64) -> proj.
// R9: GEMM main loop = exact R7 (best measured: 2-barrier, BK=64 two-slab,
// 32KB LDS, (256,3), granule-rotation swizzle, XCD producer/consumer align,
// L2 banding). R8's counted-vmcnt regressed -> GEMM loop closed.
// New: (1) QKV V-epilogue transposes through LDS (reuses staging buffer,
// stride 136) -> coalesced 16B vT stores instead of 12.6M scattered 2B
// stores. (2) attn reads V fragments DIRECT from global vT (m169 precedent:
// L2-fit staging is overhead) -> Vs LDS + prefetch deleted, LDS 18.4KB.

#define EDIM 768
#define NH 12
#define HD 64
#define BB 16
#define SN 1024
#define MTOT (BB*SN)   // 16384

typedef __attribute__((ext_vector_type(8))) short short8;
typedef __attribute__((ext_vector_type(4))) short short4v;
typedef __attribute__((ext_vector_type(4))) float f32x4;
typedef unsigned short bfr;

#if defined(__HIP_DEVICE_COMPILE__)
#if !__has_builtin(__builtin_amdgcn_mfma_f32_16x16x16bf16_1k)
#error "missing __builtin_amdgcn_mfma_f32_16x16x16bf16_1k on device"
#endif
#endif

#define MFMA32(A,B,C) __builtin_amdgcn_mfma_f32_16x16x32_bf16(A,B,C,0,0,0)
#define MFMA16(A,B,C) __builtin_amdgcn_mfma_f32_16x16x16bf16_1k(A,B,C,0,0,0)

__device__ __forceinline__ bfr f2bf(float f) {
    union { float f; unsigned int u; } v; v.f = f;
    unsigned int u = v.u;
    u += 0x7FFFu + ((u >> 16) & 1u);   // RNE
    return (bfr)(u >> 16);
}
__device__ __forceinline__ bfr f2bf_fast(float f) {
    union { float f; unsigned int u; } v; v.f = f;
    return (bfr)((v.u + 0x8000u) >> 16);
}

// async global->LDS, 16 bytes per lane; lds base must be wave-uniform.
__device__ __forceinline__ void gl2lds16(const bfr* g, bfr* l) {
    __builtin_amdgcn_global_load_lds(
        (__attribute__((address_space(1))) void*)(g),
        (__attribute__((address_space(3))) void*)(l), 16, 0, 0);
}

// ---------------- convert fp32 -> bf16 ----------------
// XCD x converts x-rows [2048x, 2048x+2048) (producer side of chain).
__global__ void k_convert(const float* __restrict__ in, bfr* __restrict__ out, int n4) {
    const int j = (blockIdx.x & 7) * 1536 + (blockIdx.x >> 3);   // 12288 blocks
    int i = j * blockDim.x + threadIdx.x;
    if (i >= n4) return;
    float4 v = ((const float4*)in)[i];
    ushort4 o;
    o.x = f2bf(v.x); o.y = f2bf(v.y); o.z = f2bf(v.z); o.w = f2bf(v.w);
    ((ushort4*)out)[i] = o;
}

// ---------------- transpose + convert: in[R][C] fp32 -> out[C][R] bf16 ----------------
__global__ void k_transpose_bf16(const float* __restrict__ in, bfr* __restrict__ out,
                                 int R, int C) {
    __shared__ float tile[32][33];
    int c0 = blockIdx.x * 32, r0 = blockIdx.y * 32;
    int tx = threadIdx.x & 31, ty = threadIdx.x >> 5;
    #pragma unroll
    for (int i = 0; i < 32; i += 8)
        tile[ty + i][tx] = in[(size_t)(r0 + ty + i) * C + c0 + tx];
    __syncthreads();
    #pragma unroll
    for (int i = 0; i < 32; i += 8)
        out[(size_t)(c0 + ty + i) * R + r0 + tx] = f2bf(tile[tx][ty + i]);
}

// ---------------- bf16 MFMA GEMM: C[M,N] = A[M,768] @ BT[N,768]^T + bias ----------------
// Main loop identical to R7. smem aliases: staging As/Bs (16K elems) and, for
// V-blocks (n0>=1536, EPI=1), a [128][136] bf16 transpose buffer (17408 elems
// = 34KB -> still 3 blocks/CU). Each 128-col block is purely q, k, or v
// (768 % 128 == 0), so the V path is block-uniform.
#define QSCALE 0.18033688011112042f   // log2(e)/8
#define PST 136   // epi transpose row stride (elems): 272B = 16B-aligned

template <int EPI>
__launch_bounds__(256, 3)
__global__ void k_gemm_bt(const bfr* __restrict__ A, const bfr* __restrict__ BT,
                          const float* __restrict__ bias, float* __restrict__ out,
                          bfr* __restrict__ qb, bfr* __restrict__ kb, bfr* __restrict__ vT) {
    __shared__ bfr smem[17408];        // staging: [0,16384); epi-T: [128][PST]
    bfr* Asm = smem;                   // As[kh] at kh*4096
    bfr* Bsm = smem + 8192;            // Bs[kh] at kh*4096

    // R7 remap: xcd owns m-tiles [16x,16x+16), 2 bands of 8, n-major in band.
    const int wgid = blockIdx.y * gridDim.x + blockIdx.x;
    const int xcd = wgid & 7;
    const int idx = wgid >> 3;
    const int half8 = gridDim.x << 3;          // 8 * gx
    const int band = idx / half8;              // 0 or 1
    const int r = idx - band * half8;
    const int n0 = (r >> 3) * 128;
    const int m0 = (xcd * 16 + band * 8 + (r & 7)) * 128;

    const int t = threadIdx.x;
    const int lane = t & 63;
    const int wave = t >> 6;
    const int wr = wave >> 1, wc = wave & 1;
    const int l15 = lane & 15, quad = lane >> 4;

    f32x4 acc[4][4] = {};

    // staging: thread t's 16B -> LDS elems [t*8,t*8+8): row=t>>2, phys gran=t&3,
    // logical (global) granule = (phys - (row>>1)) & 3.
    const int srow = t >> 2;
    const int sg = ((t & 3) - (t >> 3)) & 3;
    const bfr* gA0 = A  + (size_t)(m0 + srow) * 768 + sg * 8;
    const bfr* gA1 = A  + (size_t)(m0 + 64 + srow) * 768 + sg * 8;
    const bfr* gB0 = BT + (size_t)(n0 + srow) * 768 + sg * 8;
    const bfr* gB1 = BT + (size_t)(n0 + 64 + srow) * 768 + sg * 8;
    const int w512 = wave * 512;

    // read-side: phys granule = (quad + (row>>1)) & 3
    const int pg = ((quad + (l15 >> 1)) & 3) * 8;

    for (int kt = 0; kt < 768; kt += 64) {
        __syncthreads();                 // prev iter's ds_reads complete
        #pragma unroll
        for (int kh = 0; kh < 2; kh++) {
            const int ko = kt + kh * 32;
            gl2lds16(gA0 + ko, &Asm[kh * 4096 + w512]);
            gl2lds16(gA1 + ko, &Asm[kh * 4096 + 2048 + w512]);
            gl2lds16(gB0 + ko, &Bsm[kh * 4096 + w512]);
            gl2lds16(gB1 + ko, &Bsm[kh * 4096 + 2048 + w512]);
        }
        __syncthreads();                 // vmcnt drained: both slabs ready

        #pragma unroll
        for (int kh = 0; kh < 2; kh++) {
            short8 af[4], bf[4];
            #pragma unroll
            for (int rt = 0; rt < 4; rt++)
                af[rt] = *(const short8*)(&Asm[kh * 4096 + (wr * 64 + rt * 16 + l15) * 32 + pg]);
            #pragma unroll
            for (int ct = 0; ct < 4; ct++)
                bf[ct] = *(const short8*)(&Bsm[kh * 4096 + (wc * 64 + ct * 16 + l15) * 32 + pg]);
            #pragma unroll
            for (int rt = 0; rt < 4; rt++)
                #pragma unroll
                for (int ct = 0; ct < 4; ct++)
                    acc[rt][ct] = MFMA32(af[rt], bf[ct], acc[rt][ct]);
        }
    }

    if constexpr (EPI == 0) {
        #pragma unroll
        for (int rt = 0; rt < 4; rt++)
            #pragma unroll
            for (int ct = 0; ct < 4; ct++) {
                const int col = n0 + wc * 64 + ct * 16 + l15;
                const float bv = bias[col];
                #pragma unroll
                for (int reg = 0; reg < 4; reg++) {
                    const int m = m0 + wr * 64 + rt * 16 + quad * 4 + reg;
                    out[(size_t)m * EDIM + col] = acc[rt][ct][reg] + bv;
                }
            }
    } else if (n0 >= 1536) {
        // ---- V block: LDS transpose -> coalesced vT row stores ----
        __syncthreads();   // all waves done reading staging smem
        #pragma unroll
        for (int rt = 0; rt < 4; rt++)
            #pragma unroll
            for (int ct = 0; ct < 4; ct++) {
                const int cl = wc * 64 + ct * 16 + l15;
                const float bv = bias[n0 + cl];
                #pragma unroll
                for (int reg = 0; reg < 4; reg++) {
                    const int ml = wr * 64 + rt * 16 + quad * 4 + reg;
                    smem[cl * PST + ml] = f2bf(acc[rt][ct][reg] + bv);
                }
            }
        __syncthreads();
        // 256 threads: row rr = t>>1 (c_local), half = t&1 -> 128B each
        const int rr = t >> 1, hf = t & 1;
        const int rem = n0 + rr - 1536;
        const int h = rem >> 6, d = rem & 63;
        const int b = m0 >> 10, nb = m0 & 1023;
        bfr* dst = vT + ((size_t)(b * NH + h) * HD + d) * SN + nb + hf * 64;
        const bfr* src = smem + rr * PST + hf * 64;
        #pragma unroll
        for (int i = 0; i < 8; i++)
            *(uint4*)(dst + i * 8) = *(const uint4*)(src + i * 8);
    } else {
        // ---- q / k block: 32B-run coalesced element stores (unchanged) ----
        #pragma unroll
        for (int rt = 0; rt < 4; rt++)
            #pragma unroll
            for (int ct = 0; ct < 4; ct++) {
                const int col = n0 + wc * 64 + ct * 16 + l15;
                const float bv = bias[col];
                const int isq = (col < 768);
                const int rem = col - (isq ? 0 : 768);
                const int h = rem >> 6, d = rem & 63;
                #pragma unroll
                for (int reg = 0; reg < 4; reg++) {
                    const int m = m0 + wr * 64 + rt * 16 + quad * 4 + reg;
                    const int b = m >> 10, n = m & 1023;
                    const size_t bh = (size_t)b * NH + h;
                    float val = acc[rt][ct][reg] + bv;
                    if (isq) qb[(bh * SN + n) * HD + d] = f2bf(val * QSCALE);
                    else     kb[(bh * SN + n) * HD + d] = f2bf(val);
                }
            }
    }
}

// ---------------- flash attention: LDS K (shared), V DIRECT from global vT ----------------
#define LDK 72   // 144B row stride = 9 x 16B: aligned b128, conflict-light

__launch_bounds__(256, 2)
__global__ void k_attn(const bfr* __restrict__ qb, const bfr* __restrict__ kb,
                       const bfr* __restrict__ vT, bfr* __restrict__ ao) {
    __shared__ bfr Ks[2][64 * LDK];    // 18.4 KB

    // XCD-aligned remap: XCD x handles bh in [24x,24x+24) (batches 2x,2x+1).
    const int linear = blockIdx.y * gridDim.x + blockIdx.x;
    const int idx = linear >> 3;
    const int bh = (linear & 7) * 24 + idx % 24;
    const int q0 = (idx / 24) * 128;

    const int t = threadIdx.x;
    const int lane = t & 63, w = t >> 6;
    const int l15 = lane & 15, quad = lane >> 4;

    const bfr* qbase = qb + (size_t)bh * SN * HD;
    const bfr* kbase = kb + (size_t)bh * SN * HD;
    const bfr* vbase = vT + (size_t)bh * HD * SN;

    short8 qf[2][2];
    #pragma unroll
    for (int qt = 0; qt < 2; qt++)
        #pragma unroll
        for (int c = 0; c < 2; c++)
            qf[qt][c] = *(const short8*)(qbase + (size_t)(q0 + w * 32 + qt * 16 + l15) * HD + c * 32 + quad * 8);

    f32x4 o_acc[2][4] = {};
    f32x4 l_acc[2] = {};
    short4v ones4;
    #pragma unroll
    for (int i = 0; i < 4; i++) ones4[i] = (short)0x3F80;

    const int srow = t >> 2;
    const int scol = (t & 3) * 16;
    const bfr* gK = kbase + (size_t)srow * HD + scol;
    const int soff = srow * LDK + scol;

    uint4 kr0, kr1;
    kr0 = *(const uint4*)(gK);      kr1 = *(const uint4*)(gK + 8);
    *(uint4*)(&Ks[0][soff]) = kr0;  *(uint4*)(&Ks[0][soff + 8]) = kr1;

    for (int it = 0; it < SN / 64; it++) {
        const int cur = it & 1;
        const int kv0 = it * 64;
        const int kv0n = kv0 + 64;

        // V fragments: direct global (L2-local after XCD align); issued early,
        // consumed after QK^T + softmax -> latency covered.
        short4v vf[4][4];
        #pragma unroll
        for (int kvt = 0; kvt < 4; kvt++)
            #pragma unroll
            for (int ct = 0; ct < 4; ct++)
                vf[kvt][ct] = *(const short4v*)(vbase + (size_t)(ct * 16 + l15) * SN
                                                + kv0 + kvt * 16 + quad * 4);

        if (kv0n < SN) {
            kr0 = *(const uint4*)(gK + (size_t)kv0n * HD);
            kr1 = *(const uint4*)(gK + (size_t)kv0n * HD + 8);
        }
        __syncthreads();
        if (kv0n < SN) {
            *(uint4*)(&Ks[cur ^ 1][soff]) = kr0;
            *(uint4*)(&Ks[cur ^ 1][soff + 8]) = kr1;
        }

        const bfr* Kc = &Ks[cur][0];
        short8 kf[4][2];
        #pragma unroll
        for (int kvt = 0; kvt < 4; kvt++)
            #pragma unroll
            for (int c = 0; c < 2; c++)
                kf[kvt][c] = *(const short8*)(Kc + (kvt * 16 + l15) * LDK + c * 32 + quad * 8);

        f32x4 st[4][2] = {};
        #pragma unroll
        for (int c = 0; c < 2; c++)
            #pragma unroll
            for (int kvt = 0; kvt < 4; kvt++)
                #pragma unroll
                for (int qt = 0; qt < 2; qt++)
                    st[kvt][qt] = MFMA32(kf[kvt][c], qf[qt][c], st[kvt][qt]);

        short4v pf[4][2];
        #pragma unroll
        for (int kvt = 0; kvt < 4; kvt++)
            #pragma unroll
            for (int qt = 0; qt < 2; qt++) {
                union { unsigned u[2]; short4v s; } cv;
                cv.u[0] = (unsigned)f2bf_fast(exp2f(st[kvt][qt][0]))
                        | ((unsigned)f2bf_fast(exp2f(st[kvt][qt][1])) << 16);
                cv.u[1] = (unsigned)f2bf_fast(exp2f(st[kvt][qt][2]))
                        | ((unsigned)f2bf_fast(exp2f(st[kvt][qt][3])) << 16);
                pf[kvt][qt] = cv.s;
            }

        #pragma unroll
        for (int kvt = 0; kvt < 4; kvt++)
            #pragma unroll
            for (int qt = 0; qt < 2; qt++)
                l_acc[qt] = MFMA16(pf[kvt][qt], ones4, l_acc[qt]);
        #pragma unroll
        for (int kvt = 0; kvt < 4; kvt++)
            #pragma unroll
            for (int qt = 0; qt < 2; qt++)
                #pragma unroll
                for (int ct = 0; ct < 4; ct++)
                    o_acc[qt][ct] = MFMA16(pf[kvt][qt], vf[kvt][ct], o_acc[qt][ct]);
    }

    const int bb = bh / NH, h = bh % NH;
    #pragma unroll
    for (int qt = 0; qt < 2; qt++) {
        #pragma unroll
        for (int r = 0; r < 4; r++) {
            const float inv = 1.0f / l_acc[qt][r];
            const int n = q0 + w * 32 + qt * 16 + quad * 4 + r;
            #pragma unroll
            for (int ct = 0; ct < 4; ct++) {
                const int d = ct * 16 + l15;
                ao[((size_t)bb * SN + n) * EDIM + h * HD + d] = f2bf_fast(o_acc[qt][ct][r] * inv);
            }
        }
    }
}

extern "C" void kernel_launch(void* const* d_in, const int* in_sizes, int n_in,
                              void* d_out, int out_size, void* d_ws, size_t ws_size,
                              hipStream_t stream) {
    const float* x      = (const float*)d_in[0];
    const float* w_qkv  = (const float*)d_in[1];
    const float* b_qkv  = (const float*)d_in[2];
    const float* w_proj = (const float*)d_in[3];
    const float* b_proj = (const float*)d_in[4];

    char* ws = (char*)d_ws;
    bfr* xb     = (bfr*)(ws + 0);
    bfr* wqkvT  = (bfr*)(ws + 25165824);
    bfr* wprojT = (bfr*)(ws + 28704768);
    bfr* qb     = (bfr*)(ws + 29884416);
    bfr* kb     = (bfr*)(ws + 55050240);
    bfr* vT     = (bfr*)(ws + 80216064);
    bfr* ao     = (bfr*)(ws + 105381888);

    k_convert<<<12288, 256, 0, stream>>>(x, xb, (MTOT * EDIM) / 4);
    k_transpose_bf16<<<dim3(2304 / 32, 768 / 32), 256, 0, stream>>>(w_qkv, wqkvT, 768, 2304);
    k_transpose_bf16<<<dim3(768 / 32, 768 / 32), 256, 0, stream>>>(w_proj, wprojT, 768, 768);
    k_gemm_bt<1><<<dim3(2304 / 128, MTOT / 128), 256, 0, stream>>>(
        xb, wqkvT, b_qkv, nullptr, qb, kb, vT);
    k_attn<<<dim3(BB * NH, SN / 128), 256, 0, stream>>>(qb, kb, vT, ao);
    k_gemm_bt<0><<<dim3(768 / 128, MTOT / 128), 256, 0, stream>>>(
        ao, wprojT, b_proj, (float*)d_out, nullptr, nullptr, nullptr);
}

// Round 10
// 306.479 us; speedup vs baseline: 1.2840x; 1.2840x over previous
//
#include <hip/hip_runtime.h>
#include <hip/hip_bf16.h>

// Attention block: x[16,1024,768] -> QKV -> MHA(12 heads, d=64) -> proj.
// R10: surgical revert of R9's attn experiment. k_attn = R8/R7 version
// (LDS-staged K AND V, double-buffered, coalesced uint4 staging loads,
// XCD-aligned remap) -- R9's V-direct-from-global was 3.5x worse (198us):
// PV fragment gather from global = 16 lines/wave-load at 32B utilization.
// GEMM kept from R9: R7 main loop (2-barrier, BK=64 two-slab, 32KB LDS,
// (256,3), granule-rotation swizzle, XCD align, L2 banding) + V-epilogue
// LDS transpose -> coalesced 16B vT stores.

#define EDIM 768
#define NH 12
#define HD 64
#define BB 16
#define SN 1024
#define MTOT (BB*SN)   // 16384

typedef __attribute__((ext_vector_type(8))) short short8;
typedef __attribute__((ext_vector_type(4))) short short4v;
typedef __attribute__((ext_vector_type(4))) float f32x4;
typedef unsigned short bfr;

#if defined(__HIP_DEVICE_COMPILE__)
#if !__has_builtin(__builtin_amdgcn_mfma_f32_16x16x16bf16_1k)
#error "missing __builtin_amdgcn_mfma_f32_16x16x16bf16_1k on device"
#endif
#endif

#define MFMA32(A,B,C) __builtin_amdgcn_mfma_f32_16x16x32_bf16(A,B,C,0,0,0)
#define MFMA16(A,B,C) __builtin_amdgcn_mfma_f32_16x16x16bf16_1k(A,B,C,0,0,0)

__device__ __forceinline__ bfr f2bf(float f) {
    union { float f; unsigned int u; } v; v.f = f;
    unsigned int u = v.u;
    u += 0x7FFFu + ((u >> 16) & 1u);   // RNE
    return (bfr)(u >> 16);
}
__device__ __forceinline__ bfr f2bf_fast(float f) {
    union { float f; unsigned int u; } v; v.f = f;
    return (bfr)((v.u + 0x8000u) >> 16);
}

// async global->LDS, 16 bytes per lane; lds base must be wave-uniform.
__device__ __forceinline__ void gl2lds16(const bfr* g, bfr* l) {
    __builtin_amdgcn_global_load_lds(
        (__attribute__((address_space(1))) void*)(g),
        (__attribute__((address_space(3))) void*)(l), 16, 0, 0);
}

// ---------------- convert fp32 -> bf16 ----------------
// XCD x converts x-rows [2048x, 2048x+2048) (producer side of chain).
__global__ void k_convert(const float* __restrict__ in, bfr* __restrict__ out, int n4) {
    const int j = (blockIdx.x & 7) * 1536 + (blockIdx.x >> 3);   // 12288 blocks
    int i = j * blockDim.x + threadIdx.x;
    if (i >= n4) return;
    float4 v = ((const float4*)in)[i];
    ushort4 o;
    o.x = f2bf(v.x); o.y = f2bf(v.y); o.z = f2bf(v.z); o.w = f2bf(v.w);
    ((ushort4*)out)[i] = o;
}

// ---------------- transpose + convert: in[R][C] fp32 -> out[C][R] bf16 ----------------
__global__ void k_transpose_bf16(const float* __restrict__ in, bfr* __restrict__ out,
                                 int R, int C) {
    __shared__ float tile[32][33];
    int c0 = blockIdx.x * 32, r0 = blockIdx.y * 32;
    int tx = threadIdx.x & 31, ty = threadIdx.x >> 5;
    #pragma unroll
    for (int i = 0; i < 32; i += 8)
        tile[ty + i][tx] = in[(size_t)(r0 + ty + i) * C + c0 + tx];
    __syncthreads();
    #pragma unroll
    for (int i = 0; i < 32; i += 8)
        out[(size_t)(c0 + ty + i) * R + r0 + tx] = f2bf(tile[tx][ty + i]);
}

// ---------------- bf16 MFMA GEMM: C[M,N] = A[M,768] @ BT[N,768]^T + bias ----------------
// Main loop identical to R7. smem aliases: staging As/Bs (16K elems) and, for
// V-blocks (n0>=1536, EPI=1), a [128][136] bf16 transpose buffer (17408 elems
// = 34KB -> still 3 blocks/CU). Each 128-col block is purely q, k, or v.
#define QSCALE 0.18033688011112042f   // log2(e)/8
#define PST 136   // epi transpose row stride (elems): 272B = 16B-aligned

template <int EPI>
__launch_bounds__(256, 3)
__global__ void k_gemm_bt(const bfr* __restrict__ A, const bfr* __restrict__ BT,
                          const float* __restrict__ bias, float* __restrict__ out,
                          bfr* __restrict__ qb, bfr* __restrict__ kb, bfr* __restrict__ vT) {
    __shared__ bfr smem[17408];        // staging: [0,16384); epi-T: [128][PST]
    bfr* Asm = smem;                   // As[kh] at kh*4096
    bfr* Bsm = smem + 8192;            // Bs[kh] at kh*4096

    // R7 remap: xcd owns m-tiles [16x,16x+16), 2 bands of 8, n-major in band.
    const int wgid = blockIdx.y * gridDim.x + blockIdx.x;
    const int xcd = wgid & 7;
    const int idx = wgid >> 3;
    const int half8 = gridDim.x << 3;          // 8 * gx
    const int band = idx / half8;              // 0 or 1
    const int r = idx - band * half8;
    const int n0 = (r >> 3) * 128;
    const int m0 = (xcd * 16 + band * 8 + (r & 7)) * 128;

    const int t = threadIdx.x;
    const int lane = t & 63;
    const int wave = t >> 6;
    const int wr = wave >> 1, wc = wave & 1;
    const int l15 = lane & 15, quad = lane >> 4;

    f32x4 acc[4][4] = {};

    // staging: thread t's 16B -> LDS elems [t*8,t*8+8): row=t>>2, phys gran=t&3,
    // logical (global) granule = (phys - (row>>1)) & 3.
    const int srow = t >> 2;
    const int sg = ((t & 3) - (t >> 3)) & 3;
    const bfr* gA0 = A  + (size_t)(m0 + srow) * 768 + sg * 8;
    const bfr* gA1 = A  + (size_t)(m0 + 64 + srow) * 768 + sg * 8;
    const bfr* gB0 = BT + (size_t)(n0 + srow) * 768 + sg * 8;
    const bfr* gB1 = BT + (size_t)(n0 + 64 + srow) * 768 + sg * 8;
    const int w512 = wave * 512;

    // read-side: phys granule = (quad + (row>>1)) & 3
    const int pg = ((quad + (l15 >> 1)) & 3) * 8;

    for (int kt = 0; kt < 768; kt += 64) {
        __syncthreads();                 // prev iter's ds_reads complete
        #pragma unroll
        for (int kh = 0; kh < 2; kh++) {
            const int ko = kt + kh * 32;
            gl2lds16(gA0 + ko, &Asm[kh * 4096 + w512]);
            gl2lds16(gA1 + ko, &Asm[kh * 4096 + 2048 + w512]);
            gl2lds16(gB0 + ko, &Bsm[kh * 4096 + w512]);
            gl2lds16(gB1 + ko, &Bsm[kh * 4096 + 2048 + w512]);
        }
        __syncthreads();                 // vmcnt drained: both slabs ready

        #pragma unroll
        for (int kh = 0; kh < 2; kh++) {
            short8 af[4], bf[4];
            #pragma unroll
            for (int rt = 0; rt < 4; rt++)
                af[rt] = *(const short8*)(&Asm[kh * 4096 + (wr * 64 + rt * 16 + l15) * 32 + pg]);
            #pragma unroll
            for (int ct = 0; ct < 4; ct++)
                bf[ct] = *(const short8*)(&Bsm[kh * 4096 + (wc * 64 + ct * 16 + l15) * 32 + pg]);
            #pragma unroll
            for (int rt = 0; rt < 4; rt++)
                #pragma unroll
                for (int ct = 0; ct < 4; ct++)
                    acc[rt][ct] = MFMA32(af[rt], bf[ct], acc[rt][ct]);
        }
    }

    if constexpr (EPI == 0) {
        #pragma unroll
        for (int rt = 0; rt < 4; rt++)
            #pragma unroll
            for (int ct = 0; ct < 4; ct++) {
                const int col = n0 + wc * 64 + ct * 16 + l15;
                const float bv = bias[col];
                #pragma unroll
                for (int reg = 0; reg < 4; reg++) {
                    const int m = m0 + wr * 64 + rt * 16 + quad * 4 + reg;
                    out[(size_t)m * EDIM + col] = acc[rt][ct][reg] + bv;
                }
            }
    } else if (n0 >= 1536) {
        // ---- V block: LDS transpose -> coalesced vT row stores ----
        __syncthreads();   // all waves done reading staging smem
        #pragma unroll
        for (int rt = 0; rt < 4; rt++)
            #pragma unroll
            for (int ct = 0; ct < 4; ct++) {
                const int cl = wc * 64 + ct * 16 + l15;
                const float bv = bias[n0 + cl];
                #pragma unroll
                for (int reg = 0; reg < 4; reg++) {
                    const int ml = wr * 64 + rt * 16 + quad * 4 + reg;
                    smem[cl * PST + ml] = f2bf(acc[rt][ct][reg] + bv);
                }
            }
        __syncthreads();
        // 256 threads: row rr = t>>1 (c_local), half = t&1 -> 128B each
        const int rr = t >> 1, hf = t & 1;
        const int rem = n0 + rr - 1536;
        const int h = rem >> 6, d = rem & 63;
        const int b = m0 >> 10, nb = m0 & 1023;
        bfr* dst = vT + ((size_t)(b * NH + h) * HD + d) * SN + nb + hf * 64;
        const bfr* src = smem + rr * PST + hf * 64;
        #pragma unroll
        for (int i = 0; i < 8; i++)
            *(uint4*)(dst + i * 8) = *(const uint4*)(src + i * 8);
    } else {
        // ---- q / k block: 32B-run coalesced element stores ----
        #pragma unroll
        for (int rt = 0; rt < 4; rt++)
            #pragma unroll
            for (int ct = 0; ct < 4; ct++) {
                const int col = n0 + wc * 64 + ct * 16 + l15;
                const float bv = bias[col];
                const int isq = (col < 768);
                const int rem = col - (isq ? 0 : 768);
                const int h = rem >> 6, d = rem & 63;
                #pragma unroll
                for (int reg = 0; reg < 4; reg++) {
                    const int m = m0 + wr * 64 + rt * 16 + quad * 4 + reg;
                    const int b = m >> 10, n = m & 1023;
                    const size_t bh = (size_t)b * NH + h;
                    float val = acc[rt][ct][reg] + bv;
                    if (isq) qb[(bh * SN + n) * HD + d] = f2bf(val * QSCALE);
                    else     kb[(bh * SN + n) * HD + d] = f2bf(val);
                }
            }
    }
}

// ---------------- flash attention (R5 hybrid): LDS-staged K/V, register P ----------------
#define LDK 72   // 144B row stride = 9 x 16B: aligned b128, conflict-light

__launch_bounds__(256, 2)
__global__ void k_attn(const bfr* __restrict__ qb, const bfr* __restrict__ kb,
                       const bfr* __restrict__ vT, bfr* __restrict__ ao) {
    __shared__ bfr Ks[2][64 * LDK];
    __shared__ bfr Vs[2][64 * LDK];

    // XCD-aligned remap: XCD x handles bh in [24x,24x+24) (batches 2x,2x+1).
    const int linear = blockIdx.y * gridDim.x + blockIdx.x;
    const int idx = linear >> 3;
    const int bh = (linear & 7) * 24 + idx % 24;
    const int q0 = (idx / 24) * 128;

    const int t = threadIdx.x;
    const int lane = t & 63, w = t >> 6;
    const int l15 = lane & 15, quad = lane >> 4;

    const bfr* qbase = qb + (size_t)bh * SN * HD;
    const bfr* kbase = kb + (size_t)bh * SN * HD;
    const bfr* vbase = vT + (size_t)bh * HD * SN;

    short8 qf[2][2];
    #pragma unroll
    for (int qt = 0; qt < 2; qt++)
        #pragma unroll
        for (int c = 0; c < 2; c++)
            qf[qt][c] = *(const short8*)(qbase + (size_t)(q0 + w * 32 + qt * 16 + l15) * HD + c * 32 + quad * 8);

    f32x4 o_acc[2][4] = {};
    f32x4 l_acc[2] = {};
    short4v ones4;
    #pragma unroll
    for (int i = 0; i < 4; i++) ones4[i] = (short)0x3F80;

    const int srow = t >> 2;
    const int scol = (t & 3) * 16;
    const bfr* gK = kbase + (size_t)srow * HD + scol;
    const bfr* gV = vbase + (size_t)srow * SN + scol;
    const int soff = srow * LDK + scol;

    uint4 kr0, kr1, vr0, vr1;
    kr0 = *(const uint4*)(gK);      kr1 = *(const uint4*)(gK + 8);
    vr0 = *(const uint4*)(gV);      vr1 = *(const uint4*)(gV + 8);
    *(uint4*)(&Ks[0][soff]) = kr0;  *(uint4*)(&Ks[0][soff + 8]) = kr1;
    *(uint4*)(&Vs[0][soff]) = vr0;  *(uint4*)(&Vs[0][soff + 8]) = vr1;

    for (int it = 0; it < SN / 64; it++) {
        const int cur = it & 1;
        const int kv0n = (it + 1) * 64;
        if (kv0n < SN) {
            kr0 = *(const uint4*)(gK + (size_t)kv0n * HD);
            kr1 = *(const uint4*)(gK + (size_t)kv0n * HD + 8);
            vr0 = *(const uint4*)(gV + kv0n);
            vr1 = *(const uint4*)(gV + kv0n + 8);
        }
        __syncthreads();
        if (kv0n < SN) {
            *(uint4*)(&Ks[cur ^ 1][soff]) = kr0;  *(uint4*)(&Ks[cur ^ 1][soff + 8]) = kr1;
            *(uint4*)(&Vs[cur ^ 1][soff]) = vr0;  *(uint4*)(&Vs[cur ^ 1][soff + 8]) = vr1;
        }

        const bfr* Kc = &Ks[cur][0];
        const bfr* Vc = &Vs[cur][0];

        short8 kf[4][2];
        #pragma unroll
        for (int kvt = 0; kvt < 4; kvt++)
            #pragma unroll
            for (int c = 0; c < 2; c++)
                kf[kvt][c] = *(const short8*)(Kc + (kvt * 16 + l15) * LDK + c * 32 + quad * 8);
        short4v vf[4][4];
        #pragma unroll
        for (int kvt = 0; kvt < 4; kvt++)
            #pragma unroll
            for (int ct = 0; ct < 4; ct++)
                vf[kvt][ct] = *(const short4v*)(Vc + (ct * 16 + l15) * LDK + kvt * 16 + quad * 4);

        f32x4 st[4][2] = {};
        #pragma unroll
        for (int c = 0; c < 2; c++)
            #pragma unroll
            for (int kvt = 0; kvt < 4; kvt++)
                #pragma unroll
                for (int qt = 0; qt < 2; qt++)
                    st[kvt][qt] = MFMA32(kf[kvt][c], qf[qt][c], st[kvt][qt]);

        short4v pf[4][2];
        #pragma unroll
        for (int kvt = 0; kvt < 4; kvt++)
            #pragma unroll
            for (int qt = 0; qt < 2; qt++) {
                union { unsigned u[2]; short4v s; } cv;
                cv.u[0] = (unsigned)f2bf_fast(exp2f(st[kvt][qt][0]))
                        | ((unsigned)f2bf_fast(exp2f(st[kvt][qt][1])) << 16);
                cv.u[1] = (unsigned)f2bf_fast(exp2f(st[kvt][qt][2]))
                        | ((unsigned)f2bf_fast(exp2f(st[kvt][qt][3])) << 16);
                pf[kvt][qt] = cv.s;
            }

        #pragma unroll
        for (int kvt = 0; kvt < 4; kvt++)
            #pragma unroll
            for (int qt = 0; qt < 2; qt++)
                l_acc[qt] = MFMA16(pf[kvt][qt], ones4, l_acc[qt]);
        #pragma unroll
        for (int kvt = 0; kvt < 4; kvt++)
            #pragma unroll
            for (int qt = 0; qt < 2; qt++)
                #pragma unroll
                for (int ct = 0; ct < 4; ct++)
                    o_acc[qt][ct] = MFMA16(pf[kvt][qt], vf[kvt][ct], o_acc[qt][ct]);
    }

    const int bb = bh / NH, h = bh % NH;
    #pragma unroll
    for (int qt = 0; qt < 2; qt++) {
        #pragma unroll
        for (int r = 0; r < 4; r++) {
            const float inv = 1.0f / l_acc[qt][r];
            const int n = q0 + w * 32 + qt * 16 + quad * 4 + r;
            #pragma unroll
            for (int ct = 0; ct < 4; ct++) {
                const int d = ct * 16 + l15;
                ao[((size_t)bb * SN + n) * EDIM + h * HD + d] = f2bf_fast(o_acc[qt][ct][r] * inv);
            }
        }
    }
}

extern "C" void kernel_launch(void* const* d_in, const int* in_sizes, int n_in,
                              void* d_out, int out_size, void* d_ws, size_t ws_size,
                              hipStream_t stream) {
    const float* x      = (const float*)d_in[0];
    const float* w_qkv  = (const float*)d_in[1];
    const float* b_qkv  = (const float*)d_in[2];
    const float* w_proj = (const float*)d_in[3];
    const float* b_proj = (const float*)d_in[4];

    char* ws = (char*)d_ws;
    bfr* xb     = (bfr*)(ws + 0);
    bfr* wqkvT  = (bfr*)(ws + 25165824);
    bfr* wprojT = (bfr*)(ws + 28704768);
    bfr* qb     = (bfr*)(ws + 29884416);
    bfr* kb     = (bfr*)(ws + 55050240);
    bfr* vT     = (bfr*)(ws + 80216064);
    bfr* ao     = (bfr*)(ws + 105381888);

    k_convert<<<12288, 256, 0, stream>>>(x, xb, (MTOT * EDIM) / 4);
    k_transpose_bf16<<<dim3(2304 / 32, 768 / 32), 256, 0, stream>>>(w_qkv, wqkvT, 768, 2304);
    k_transpose_bf16<<<dim3(768 / 32, 768 / 32), 256, 0, stream>>>(w_proj, wprojT, 768, 768);
    k_gemm_bt<1><<<dim3(2304 / 128, MTOT / 128), 256, 0, stream>>>(
        xb, wqkvT, b_qkv, nullptr, qb, kb, vT);
    k_attn<<<dim3(BB * NH, SN / 128), 256, 0, stream>>>(qb, kb, vT, ao);
    k_gemm_bt<0><<<dim3(768 / 128, MTOT / 128), 256, 0, stream>>>(
        ao, wprojT, b_proj, (float*)d_out, nullptr, nullptr, nullptr);
}

// Round 11
// 294.743 us; speedup vs baseline: 1.3351x; 1.0398x over previous
//
#include <hip/hip_runtime.h>
#include <hip/hip_bf16.h>

// Attention block: x[16,1024,768] -> QKV -> MHA(12 heads, d=64) -> proj.
// R11: attn occupancy + L2 banding. R10 counters: attn is now the top kernel
// (96.5us, VALUBusy 66%, MfmaUtil 39%, Occupancy 26.7% = 2 blocks/CU,
// FETCH 131MB vs 75MB compulsory). Fixes:
//  (1) __launch_bounds__(256,4): LDS 36.9KB -> 4 blocks/CU fit (147<160KB);
//      VGPR 68+~40acc=~108 <= 128 cap -> no spill. Doubles cross-wave
//      MFMA/VALU overlap to hide the serial QK^T->exp->PV chain.
//  (2) bh-banded XCD remap: 2 bands of 12 bh (3MB K/V < 4MB L2/XCD),
//      q-major within band -> K/V L2-resident per band.
// GEMM unchanged from R10 (R7 loop + V-epilogue LDS transpose).

#define EDIM 768
#define NH 12
#define HD 64
#define BB 16
#define SN 1024
#define MTOT (BB*SN)   // 16384

typedef __attribute__((ext_vector_type(8))) short short8;
typedef __attribute__((ext_vector_type(4))) short short4v;
typedef __attribute__((ext_vector_type(4))) float f32x4;
typedef unsigned short bfr;

#if defined(__HIP_DEVICE_COMPILE__)
#if !__has_builtin(__builtin_amdgcn_mfma_f32_16x16x16bf16_1k)
#error "missing __builtin_amdgcn_mfma_f32_16x16x16bf16_1k on device"
#endif
#endif

#define MFMA32(A,B,C) __builtin_amdgcn_mfma_f32_16x16x32_bf16(A,B,C,0,0,0)
#define MFMA16(A,B,C) __builtin_amdgcn_mfma_f32_16x16x16bf16_1k(A,B,C,0,0,0)

__device__ __forceinline__ bfr f2bf(float f) {
    union { float f; unsigned int u; } v; v.f = f;
    unsigned int u = v.u;
    u += 0x7FFFu + ((u >> 16) & 1u);   // RNE
    return (bfr)(u >> 16);
}
__device__ __forceinline__ bfr f2bf_fast(float f) {
    union { float f; unsigned int u; } v; v.f = f;
    return (bfr)((v.u + 0x8000u) >> 16);
}

// async global->LDS, 16 bytes per lane; lds base must be wave-uniform.
__device__ __forceinline__ void gl2lds16(const bfr* g, bfr* l) {
    __builtin_amdgcn_global_load_lds(
        (__attribute__((address_space(1))) void*)(g),
        (__attribute__((address_space(3))) void*)(l), 16, 0, 0);
}

// ---------------- convert fp32 -> bf16 ----------------
// XCD x converts x-rows [2048x, 2048x+2048) (producer side of chain).
__global__ void k_convert(const float* __restrict__ in, bfr* __restrict__ out, int n4) {
    const int j = (blockIdx.x & 7) * 1536 + (blockIdx.x >> 3);   // 12288 blocks
    int i = j * blockDim.x + threadIdx.x;
    if (i >= n4) return;
    float4 v = ((const float4*)in)[i];
    ushort4 o;
    o.x = f2bf(v.x); o.y = f2bf(v.y); o.z = f2bf(v.z); o.w = f2bf(v.w);
    ((ushort4*)out)[i] = o;
}

// ---------------- transpose + convert: in[R][C] fp32 -> out[C][R] bf16 ----------------
__global__ void k_transpose_bf16(const float* __restrict__ in, bfr* __restrict__ out,
                                 int R, int C) {
    __shared__ float tile[32][33];
    int c0 = blockIdx.x * 32, r0 = blockIdx.y * 32;
    int tx = threadIdx.x & 31, ty = threadIdx.x >> 5;
    #pragma unroll
    for (int i = 0; i < 32; i += 8)
        tile[ty + i][tx] = in[(size_t)(r0 + ty + i) * C + c0 + tx];
    __syncthreads();
    #pragma unroll
    for (int i = 0; i < 32; i += 8)
        out[(size_t)(c0 + ty + i) * R + r0 + tx] = f2bf(tile[tx][ty + i]);
}

// ---------------- bf16 MFMA GEMM: C[M,N] = A[M,768] @ BT[N,768]^T + bias ----------------
// Main loop identical to R7. smem aliases: staging As/Bs (16K elems) and, for
// V-blocks (n0>=1536, EPI=1), a [128][136] bf16 transpose buffer (17408 elems
// = 34KB -> still 3 blocks/CU). Each 128-col block is purely q, k, or v.
#define QSCALE 0.18033688011112042f   // log2(e)/8
#define PST 136   // epi transpose row stride (elems): 272B = 16B-aligned

template <int EPI>
__launch_bounds__(256, 3)
__global__ void k_gemm_bt(const bfr* __restrict__ A, const bfr* __restrict__ BT,
                          const float* __restrict__ bias, float* __restrict__ out,
                          bfr* __restrict__ qb, bfr* __restrict__ kb, bfr* __restrict__ vT) {
    __shared__ bfr smem[17408];        // staging: [0,16384); epi-T: [128][PST]
    bfr* Asm = smem;                   // As[kh] at kh*4096
    bfr* Bsm = smem + 8192;            // Bs[kh] at kh*4096

    // R7 remap: xcd owns m-tiles [16x,16x+16), 2 bands of 8, n-major in band.
    const int wgid = blockIdx.y * gridDim.x + blockIdx.x;
    const int xcd = wgid & 7;
    const int idx = wgid >> 3;
    const int half8 = gridDim.x << 3;          // 8 * gx
    const int band = idx / half8;              // 0 or 1
    const int r = idx - band * half8;
    const int n0 = (r >> 3) * 128;
    const int m0 = (xcd * 16 + band * 8 + (r & 7)) * 128;

    const int t = threadIdx.x;
    const int lane = t & 63;
    const int wave = t >> 6;
    const int wr = wave >> 1, wc = wave & 1;
    const int l15 = lane & 15, quad = lane >> 4;

    f32x4 acc[4][4] = {};

    // staging: thread t's 16B -> LDS elems [t*8,t*8+8): row=t>>2, phys gran=t&3,
    // logical (global) granule = (phys - (row>>1)) & 3.
    const int srow = t >> 2;
    const int sg = ((t & 3) - (t >> 3)) & 3;
    const bfr* gA0 = A  + (size_t)(m0 + srow) * 768 + sg * 8;
    const bfr* gA1 = A  + (size_t)(m0 + 64 + srow) * 768 + sg * 8;
    const bfr* gB0 = BT + (size_t)(n0 + srow) * 768 + sg * 8;
    const bfr* gB1 = BT + (size_t)(n0 + 64 + srow) * 768 + sg * 8;
    const int w512 = wave * 512;

    // read-side: phys granule = (quad + (row>>1)) & 3
    const int pg = ((quad + (l15 >> 1)) & 3) * 8;

    for (int kt = 0; kt < 768; kt += 64) {
        __syncthreads();                 // prev iter's ds_reads complete
        #pragma unroll
        for (int kh = 0; kh < 2; kh++) {
            const int ko = kt + kh * 32;
            gl2lds16(gA0 + ko, &Asm[kh * 4096 + w512]);
            gl2lds16(gA1 + ko, &Asm[kh * 4096 + 2048 + w512]);
            gl2lds16(gB0 + ko, &Bsm[kh * 4096 + w512]);
            gl2lds16(gB1 + ko, &Bsm[kh * 4096 + 2048 + w512]);
        }
        __syncthreads();                 // vmcnt drained: both slabs ready

        #pragma unroll
        for (int kh = 0; kh < 2; kh++) {
            short8 af[4], bf[4];
            #pragma unroll
            for (int rt = 0; rt < 4; rt++)
                af[rt] = *(const short8*)(&Asm[kh * 4096 + (wr * 64 + rt * 16 + l15) * 32 + pg]);
            #pragma unroll
            for (int ct = 0; ct < 4; ct++)
                bf[ct] = *(const short8*)(&Bsm[kh * 4096 + (wc * 64 + ct * 16 + l15) * 32 + pg]);
            #pragma unroll
            for (int rt = 0; rt < 4; rt++)
                #pragma unroll
                for (int ct = 0; ct < 4; ct++)
                    acc[rt][ct] = MFMA32(af[rt], bf[ct], acc[rt][ct]);
        }
    }

    if constexpr (EPI == 0) {
        #pragma unroll
        for (int rt = 0; rt < 4; rt++)
            #pragma unroll
            for (int ct = 0; ct < 4; ct++) {
                const int col = n0 + wc * 64 + ct * 16 + l15;
                const float bv = bias[col];
                #pragma unroll
                for (int reg = 0; reg < 4; reg++) {
                    const int m = m0 + wr * 64 + rt * 16 + quad * 4 + reg;
                    out[(size_t)m * EDIM + col] = acc[rt][ct][reg] + bv;
                }
            }
    } else if (n0 >= 1536) {
        // ---- V block: LDS transpose -> coalesced vT row stores ----
        __syncthreads();   // all waves done reading staging smem
        #pragma unroll
        for (int rt = 0; rt < 4; rt++)
            #pragma unroll
            for (int ct = 0; ct < 4; ct++) {
                const int cl = wc * 64 + ct * 16 + l15;
                const float bv = bias[n0 + cl];
                #pragma unroll
                for (int reg = 0; reg < 4; reg++) {
                    const int ml = wr * 64 + rt * 16 + quad * 4 + reg;
                    smem[cl * PST + ml] = f2bf(acc[rt][ct][reg] + bv);
                }
            }
        __syncthreads();
        // 256 threads: row rr = t>>1 (c_local), half = t&1 -> 128B each
        const int rr = t >> 1, hf = t & 1;
        const int rem = n0 + rr - 1536;
        const int h = rem >> 6, d = rem & 63;
        const int b = m0 >> 10, nb = m0 & 1023;
        bfr* dst = vT + ((size_t)(b * NH + h) * HD + d) * SN + nb + hf * 64;
        const bfr* src = smem + rr * PST + hf * 64;
        #pragma unroll
        for (int i = 0; i < 8; i++)
            *(uint4*)(dst + i * 8) = *(const uint4*)(src + i * 8);
    } else {
        // ---- q / k block: 32B-run coalesced element stores ----
        #pragma unroll
        for (int rt = 0; rt < 4; rt++)
            #pragma unroll
            for (int ct = 0; ct < 4; ct++) {
                const int col = n0 + wc * 64 + ct * 16 + l15;
                const float bv = bias[col];
                const int isq = (col < 768);
                const int rem = col - (isq ? 0 : 768);
                const int h = rem >> 6, d = rem & 63;
                #pragma unroll
                for (int reg = 0; reg < 4; reg++) {
                    const int m = m0 + wr * 64 + rt * 16 + quad * 4 + reg;
                    const int b = m >> 10, n = m & 1023;
                    const size_t bh = (size_t)b * NH + h;
                    float val = acc[rt][ct][reg] + bv;
                    if (isq) qb[(bh * SN + n) * HD + d] = f2bf(val * QSCALE);
                    else     kb[(bh * SN + n) * HD + d] = f2bf(val);
                }
            }
    }
}

// ---------------- flash attention (R5 hybrid): LDS-staged K/V, register P ----------------
#define LDK 72   // 144B row stride = 9 x 16B: aligned b128, conflict-light

__launch_bounds__(256, 4)
__global__ void k_attn(const bfr* __restrict__ qb, const bfr* __restrict__ kb,
                       const bfr* __restrict__ vT, bfr* __restrict__ ao) {
    __shared__ bfr Ks[2][64 * LDK];
    __shared__ bfr Vs[2][64 * LDK];    // total 36.9 KB -> 4 blocks/CU

    // XCD + bh-band remap: xcd = linear&7 handles bh in [24x,24x+24);
    // 2 bands of 12 bh (K/V set 3MB < 4MB L2), q-major within band,
    // bh-fastest: j = linear>>3 in [0,192); band = j/96; w = j%96;
    // bh = 24*xcd + 12*band + w%12; q0 = (w/12)*128. Bijective.
    const int linear = blockIdx.y * gridDim.x + blockIdx.x;
    const int xcd = linear & 7;
    const int j = linear >> 3;
    const int band = j / 96;
    const int wj = j - band * 96;
    const int bh = xcd * 24 + band * 12 + wj % 12;
    const int q0 = (wj / 12) * 128;

    const int t = threadIdx.x;
    const int lane = t & 63, w = t >> 6;
    const int l15 = lane & 15, quad = lane >> 4;

    const bfr* qbase = qb + (size_t)bh * SN * HD;
    const bfr* kbase = kb + (size_t)bh * SN * HD;
    const bfr* vbase = vT + (size_t)bh * HD * SN;

    short8 qf[2][2];
    #pragma unroll
    for (int qt = 0; qt < 2; qt++)
        #pragma unroll
        for (int c = 0; c < 2; c++)
            qf[qt][c] = *(const short8*)(qbase + (size_t)(q0 + w * 32 + qt * 16 + l15) * HD + c * 32 + quad * 8);

    f32x4 o_acc[2][4] = {};
    f32x4 l_acc[2] = {};
    short4v ones4;
    #pragma unroll
    for (int i = 0; i < 4; i++) ones4[i] = (short)0x3F80;

    const int srow = t >> 2;
    const int scol = (t & 3) * 16;
    const bfr* gK = kbase + (size_t)srow * HD + scol;
    const bfr* gV = vbase + (size_t)srow * SN + scol;
    const int soff = srow * LDK + scol;

    uint4 kr0, kr1, vr0, vr1;
    kr0 = *(const uint4*)(gK);      kr1 = *(const uint4*)(gK + 8);
    vr0 = *(const uint4*)(gV);      vr1 = *(const uint4*)(gV + 8);
    *(uint4*)(&Ks[0][soff]) = kr0;  *(uint4*)(&Ks[0][soff + 8]) = kr1;
    *(uint4*)(&Vs[0][soff]) = vr0;  *(uint4*)(&Vs[0][soff + 8]) = vr1;

    for (int it = 0; it < SN / 64; it++) {
        const int cur = it & 1;
        const int kv0n = (it + 1) * 64;
        if (kv0n < SN) {
            kr0 = *(const uint4*)(gK + (size_t)kv0n * HD);
            kr1 = *(const uint4*)(gK + (size_t)kv0n * HD + 8);
            vr0 = *(const uint4*)(gV + kv0n);
            vr1 = *(const uint4*)(gV + kv0n + 8);
        }
        __syncthreads();
        if (kv0n < SN) {
            *(uint4*)(&Ks[cur ^ 1][soff]) = kr0;  *(uint4*)(&Ks[cur ^ 1][soff + 8]) = kr1;
            *(uint4*)(&Vs[cur ^ 1][soff]) = vr0;  *(uint4*)(&Vs[cur ^ 1][soff + 8]) = vr1;
        }

        const bfr* Kc = &Ks[cur][0];
        const bfr* Vc = &Vs[cur][0];

        short8 kf[4][2];
        #pragma unroll
        for (int kvt = 0; kvt < 4; kvt++)
            #pragma unroll
            for (int c = 0; c < 2; c++)
                kf[kvt][c] = *(const short8*)(Kc + (kvt * 16 + l15) * LDK + c * 32 + quad * 8);
        short4v vf[4][4];
        #pragma unroll
        for (int kvt = 0; kvt < 4; kvt++)
            #pragma unroll
            for (int ct = 0; ct < 4; ct++)
                vf[kvt][ct] = *(const short4v*)(Vc + (ct * 16 + l15) * LDK + kvt * 16 + quad * 4);

        f32x4 st[4][2] = {};
        #pragma unroll
        for (int c = 0; c < 2; c++)
            #pragma unroll
            for (int kvt = 0; kvt < 4; kvt++)
                #pragma unroll
                for (int qt = 0; qt < 2; qt++)
                    st[kvt][qt] = MFMA32(kf[kvt][c], qf[qt][c], st[kvt][qt]);

        short4v pf[4][2];
        #pragma unroll
        for (int kvt = 0; kvt < 4; kvt++)
            #pragma unroll
            for (int qt = 0; qt < 2; qt++) {
                union { unsigned u[2]; short4v s; } cv;
                cv.u[0] = (unsigned)f2bf_fast(exp2f(st[kvt][qt][0]))
                        | ((unsigned)f2bf_fast(exp2f(st[kvt][qt][1])) << 16);
                cv.u[1] = (unsigned)f2bf_fast(exp2f(st[kvt][qt][2]))
                        | ((unsigned)f2bf_fast(exp2f(st[kvt][qt][3])) << 16);
                pf[kvt][qt] = cv.s;
            }

        #pragma unroll
        for (int kvt = 0; kvt < 4; kvt++)
            #pragma unroll
            for (int qt = 0; qt < 2; qt++)
                l_acc[qt] = MFMA16(pf[kvt][qt], ones4, l_acc[qt]);
        #pragma unroll
        for (int kvt = 0; kvt < 4; kvt++)
            #pragma unroll
            for (int qt = 0; qt < 2; qt++)
                #pragma unroll
                for (int ct = 0; ct < 4; ct++)
                    o_acc[qt][ct] = MFMA16(pf[kvt][qt], vf[kvt][ct], o_acc[qt][ct]);
    }

    const int bb = bh / NH, h = bh % NH;
    #pragma unroll
    for (int qt = 0; qt < 2; qt++) {
        #pragma unroll
        for (int r = 0; r < 4; r++) {
            const float inv = 1.0f / l_acc[qt][r];
            const int n = q0 + w * 32 + qt * 16 + quad * 4 + r;
            #pragma unroll
            for (int ct = 0; ct < 4; ct++) {
                const int d = ct * 16 + l15;
                ao[((size_t)bb * SN + n) * EDIM + h * HD + d] = f2bf_fast(o_acc[qt][ct][r] * inv);
            }
        }
    }
}

extern "C" void kernel_launch(void* const* d_in, const int* in_sizes, int n_in,
                              void* d_out, int out_size, void* d_ws, size_t ws_size,
                              hipStream_t stream) {
    const float* x      = (const float*)d_in[0];
    const float* w_qkv  = (const float*)d_in[1];
    const float* b_qkv  = (const float*)d_in[2];
    const float* w_proj = (const float*)d_in[3];
    const float* b_proj = (const float*)d_in[4];

    char* ws = (char*)d_ws;
    bfr* xb     = (bfr*)(ws + 0);
    bfr* wqkvT  = (bfr*)(ws + 25165824);
    bfr* wprojT = (bfr*)(ws + 28704768);
    bfr* qb     = (bfr*)(ws + 29884416);
    bfr* kb     = (bfr*)(ws + 55050240);
    bfr* vT     = (bfr*)(ws + 80216064);
    bfr* ao     = (bfr*)(ws + 105381888);

    k_convert<<<12288, 256, 0, stream>>>(x, xb, (MTOT * EDIM) / 4);
    k_transpose_bf16<<<dim3(2304 / 32, 768 / 32), 256, 0, stream>>>(w_qkv, wqkvT, 768, 2304);
    k_transpose_bf16<<<dim3(768 / 32, 768 / 32), 256, 0, stream>>>(w_proj, wprojT, 768, 768);
    k_gemm_bt<1><<<dim3(2304 / 128, MTOT / 128), 256, 0, stream>>>(
        xb, wqkvT, b_qkv, nullptr, qb, kb, vT);
    k_attn<<<dim3(BB * NH, SN / 128), 256, 0, stream>>>(qb, kb, vT, ao);
    k_gemm_bt<0><<<dim3(768 / 128, MTOT / 128), 256, 0, stream>>>(
        ao, wprojT, b_proj, (float*)d_out, nullptr, nullptr, nullptr);
}